// Round 2
// baseline (366.636 us; speedup 1.0000x reference)
//
#include <hip/hip_runtime.h>

#define B_ROWS 32768
#define D_DIM 768
#define H_DIM 64
#define E_NUM 7
#define BM 64
#define PERM_CAP (B_ROWS + E_NUM * BM)   // 33216
#define NBLOCKS_MAIN (PERM_CAP / BM)     // 519
#define W_ELEMS (E_NUM * D_DIM * H_DIM)  // 344064

// ---- ws layout (bytes) ----
#define WS_COUNTS 0
#define WS_BASE   64
#define WS_CURSOR 128
#define WS_PERM   256
#define WS_W      133120                  // 256 + 33216*4 = 133120 (256B aligned)
#define WS_WSZ    (W_ELEMS * 2)           // 688128 bytes per weight plane
#define WS_NEEDED (WS_W + 4 * WS_WSZ)     // 2,885,632

typedef __attribute__((ext_vector_type(8))) short short8;
typedef __attribute__((ext_vector_type(8))) __bf16 bf16x8;
typedef __attribute__((ext_vector_type(4))) float f32x4;

__device__ __forceinline__ unsigned short f2bf(float f) {
  // RNE float->bf16 (finite inputs only)
  unsigned int u = __float_as_uint(f);
  unsigned int r = (u + 0x7fffu + ((u >> 16) & 1u)) >> 16;
  return (unsigned short)r;
}
__device__ __forceinline__ float bf2f(unsigned short s) {
  return __uint_as_float(((unsigned int)s) << 16);
}

__device__ __forceinline__ f32x4 mfma16(short8 a, short8 b, f32x4 c) {
  return __builtin_amdgcn_mfma_f32_16x16x32_bf16(
      __builtin_bit_cast(bf16x8, a), __builtin_bit_cast(bf16x8, b), c, 0, 0, 0);
}

// ---------------- routing kernels ----------------
__global__ void k_init(int* counts, int* perm) {
  int i = blockIdx.x * 256 + threadIdx.x;
  if (i < PERM_CAP) perm[i] = -1;
  if (blockIdx.x == 0 && threadIdx.x < 16) counts[threadIdx.x] = 0;
}

__global__ void k_hist(const int* __restrict__ eid, int* __restrict__ counts) {
  __shared__ int lc[E_NUM];
  if (threadIdx.x < E_NUM) lc[threadIdx.x] = 0;
  __syncthreads();
  int i = blockIdx.x * 256 + threadIdx.x;
  int e = eid[i];
  e = e < 0 ? 0 : (e >= E_NUM ? E_NUM - 1 : e);
  atomicAdd(&lc[e], 1);
  __syncthreads();
  if (threadIdx.x < E_NUM) atomicAdd(&counts[threadIdx.x], lc[threadIdx.x]);
}

__global__ void k_scan(const int* __restrict__ counts, int* __restrict__ base,
                       int* __restrict__ cursor) {
  if (threadIdx.x == 0) {
    int run = 0;
    for (int e = 0; e < E_NUM; ++e) {
      base[e] = run;
      cursor[e] = run;
      run += ((counts[e] + BM - 1) / BM) * BM;
    }
    base[E_NUM] = run;
  }
}

__global__ void k_scatter(const int* __restrict__ eid, int* __restrict__ cursor,
                          int* __restrict__ perm) {
  __shared__ int lc[E_NUM];
  __shared__ int lb[E_NUM];
  if (threadIdx.x < E_NUM) lc[threadIdx.x] = 0;
  __syncthreads();
  int i = blockIdx.x * 256 + threadIdx.x;
  int e = eid[i];
  e = e < 0 ? 0 : (e >= E_NUM ? E_NUM - 1 : e);
  int lpos = atomicAdd(&lc[e], 1);
  __syncthreads();
  if (threadIdx.x < E_NUM) lb[threadIdx.x] = atomicAdd(&cursor[threadIdx.x], lc[threadIdx.x]);
  __syncthreads();
  perm[lb[e] + lpos] = i;
}

// ---------------- weight split/transpose ----------------
// W1 (E,D,H) -> w1{hi,lo}[e][h][d]   (B-operand of GEMM1, contiguous in d)
// W2 (E,H,D) -> w2{hi,lo}[e][d][h]   (B-operand of GEMM2, contiguous in h)
__global__ void k_convert(const float* __restrict__ W1, const float* __restrict__ W2,
                          short* __restrict__ w1hi, short* __restrict__ w1lo,
                          short* __restrict__ w2hi, short* __restrict__ w2lo) {
  int idx = blockIdx.x * 256 + threadIdx.x;
  if (idx < W_ELEMS) {
    int e = idx / (H_DIM * D_DIM);
    int rem = idx - e * (H_DIM * D_DIM);
    int h = rem / D_DIM;
    int d = rem - h * D_DIM;
    float v = W1[(size_t)e * D_DIM * H_DIM + (size_t)d * H_DIM + h];
    unsigned short hi = f2bf(v);
    w1hi[idx] = (short)hi;
    w1lo[idx] = (short)f2bf(v - bf2f(hi));
  } else if (idx < 2 * W_ELEMS) {
    int o = idx - W_ELEMS;
    int e = o / (D_DIM * H_DIM);
    int rem = o - e * (D_DIM * H_DIM);
    int d = rem / H_DIM;
    int h = rem - d * H_DIM;
    float v = W2[(size_t)e * H_DIM * D_DIM + (size_t)h * D_DIM + d];
    unsigned short hi = f2bf(v);
    w2hi[o] = (short)hi;
    w2lo[o] = (short)f2bf(v - bf2f(hi));
  }
}

// ---------------- main fused kernel ----------------
// 519 blocks x 256 thr (4 waves). Block handles 64 permuted rows, one expert.
// GEMM1: h[64x64] = x[64x768] @ W1[e]  (split-bf16, 3 MFMA per step)
// GEMM2: y[64x768] = relu(h+b1) @ W2[e]; out = x + y + b2 (scatter rows)
__global__ __launch_bounds__(256, 2) void k_adapter(
    const float* __restrict__ x, const float* __restrict__ b1,
    const float* __restrict__ b2, const short* __restrict__ w1hi,
    const short* __restrict__ w1lo, const short* __restrict__ w2hi,
    const short* __restrict__ w2lo, const int* __restrict__ base,
    const int* __restrict__ perm, float* __restrict__ out) {
  // stride 72 -> 144B rows: ds_read_b128 across 16 lanes is only 2-way bank
  // aliased (free per m136)
  __shared__ __align__(16) short hl_hi[4][16][72];
  __shared__ __align__(16) short hl_lo[4][16][72];

  const int tid = threadIdx.x;
  const int wid = tid >> 6;
  const int lane = tid & 63;
  const int l15 = lane & 15;
  const int kg = lane >> 4;  // 0..3
  const int m0 = blockIdx.x * BM;

  int e = 0;
#pragma unroll
  for (int i = 1; i < E_NUM; ++i)
    if (m0 >= base[i]) e = i;

  // A-load row (row index within tile = l15)
  const int ar = perm[m0 + wid * 16 + l15];
  const int arr = ar < 0 ? 0 : ar;
  const float* xrow = x + (size_t)arr * D_DIM;

  const short* w1h = w1hi + (size_t)e * H_DIM * D_DIM;
  const short* w1l = w1lo + (size_t)e * H_DIM * D_DIM;

  f32x4 acc1[4] = {{0.f, 0.f, 0.f, 0.f},
                   {0.f, 0.f, 0.f, 0.f},
                   {0.f, 0.f, 0.f, 0.f},
                   {0.f, 0.f, 0.f, 0.f}};

  for (int kt = 0; kt < D_DIM; kt += 32) {
    const int k0 = kt + kg * 8;
    f32x4 xa = *reinterpret_cast<const f32x4*>(xrow + k0);
    f32x4 xb = *reinterpret_cast<const f32x4*>(xrow + k0 + 4);
    short8 ahi, alo;
#pragma unroll
    for (int i = 0; i < 4; ++i) {
      unsigned short h0 = f2bf(xa[i]);
      ahi[i] = (short)h0;
      alo[i] = (short)f2bf(xa[i] - bf2f(h0));
      unsigned short h1 = f2bf(xb[i]);
      ahi[4 + i] = (short)h1;
      alo[4 + i] = (short)f2bf(xb[i] - bf2f(h1));
    }
#pragma unroll
    for (int n = 0; n < 4; ++n) {
      const size_t boff = (size_t)(n * 16 + l15) * D_DIM + k0;
      short8 bhi = *reinterpret_cast<const short8*>(w1h + boff);
      short8 blo = *reinterpret_cast<const short8*>(w1l + boff);
      acc1[n] = mfma16(ahi, bhi, acc1[n]);
      acc1[n] = mfma16(ahi, blo, acc1[n]);
      acc1[n] = mfma16(alo, bhi, acc1[n]);
    }
  }

  // bias + relu, split to bf16 hi/lo, park in LDS to re-layout C->A-frag
#pragma unroll
  for (int n = 0; n < 4; ++n) {
    const float bv = b1[e * H_DIM + n * 16 + l15];
#pragma unroll
    for (int j = 0; j < 4; ++j) {
      float v = acc1[n][j] + bv;
      v = v > 0.f ? v : 0.f;
      unsigned short hh = f2bf(v);
      const int r = kg * 4 + j;
      hl_hi[wid][r][n * 16 + l15] = (short)hh;
      hl_lo[wid][r][n * 16 + l15] = (short)f2bf(v - bf2f(hh));
    }
  }
  __syncthreads();

  // A2 fragments (row = l15, k = kg*8 + ks*32 + j)
  short8 a2h[2], a2l[2];
#pragma unroll
  for (int ks = 0; ks < 2; ++ks) {
    a2h[ks] = *reinterpret_cast<const short8*>(&hl_hi[wid][l15][ks * 32 + kg * 8]);
    a2l[ks] = *reinterpret_cast<const short8*>(&hl_lo[wid][l15][ks * 32 + kg * 8]);
  }

  // C rows for this lane (row = kg*4 + j)
  int crow[4];
#pragma unroll
  for (int j = 0; j < 4; ++j) crow[j] = perm[m0 + wid * 16 + kg * 4 + j];

  const short* w2h = w2hi + (size_t)e * D_DIM * H_DIM;
  const short* w2l = w2lo + (size_t)e * D_DIM * H_DIM;
  const float* b2e = b2 + e * D_DIM;

  for (int c = 0; c < D_DIM / 16; ++c) {
    f32x4 acc2 = {0.f, 0.f, 0.f, 0.f};
    const int col = c * 16 + l15;
#pragma unroll
    for (int ks = 0; ks < 2; ++ks) {
      const size_t boff = (size_t)col * H_DIM + ks * 32 + kg * 8;
      short8 bhi = *reinterpret_cast<const short8*>(w2h + boff);
      short8 blo = *reinterpret_cast<const short8*>(w2l + boff);
      acc2 = mfma16(a2h[ks], bhi, acc2);
      acc2 = mfma16(a2h[ks], blo, acc2);
      acc2 = mfma16(a2l[ks], bhi, acc2);
    }
    const float bv = b2e[col];
#pragma unroll
    for (int j = 0; j < 4; ++j) {
      const int r = crow[j];
      if (r >= 0) {
        const size_t o = (size_t)r * D_DIM + col;
        out[o] = acc2[j] + bv + x[o];
      }
    }
  }
}

// ---------------- fp32 fallback (used only if ws too small) ----------------
__global__ void k_fallback(const float* __restrict__ x, const int* __restrict__ eid,
                           const float* __restrict__ W1, const float* __restrict__ b1,
                           const float* __restrict__ W2, const float* __restrict__ b2,
                           float* __restrict__ out) {
  __shared__ float xs[D_DIM];
  __shared__ float hs[H_DIM];
  const int row = blockIdx.x;
  int e = eid[row];
  e = e < 0 ? 0 : (e >= E_NUM ? E_NUM - 1 : e);
  const float* xr = x + (size_t)row * D_DIM;
  for (int i = threadIdx.x; i < D_DIM; i += 256) xs[i] = xr[i];
  __syncthreads();
  if (threadIdx.x < H_DIM) {
    const float* w = W1 + (size_t)e * D_DIM * H_DIM + threadIdx.x;
    float acc = b1[e * H_DIM + threadIdx.x];
    for (int d = 0; d < D_DIM; ++d) acc += xs[d] * w[(size_t)d * H_DIM];
    hs[threadIdx.x] = acc > 0.f ? acc : 0.f;
  }
  __syncthreads();
  for (int c = threadIdx.x; c < D_DIM; c += 256) {
    const float* w = W2 + (size_t)e * H_DIM * D_DIM + c;
    float acc = b2[e * D_DIM + c];
    for (int h = 0; h < H_DIM; ++h) acc += hs[h] * w[(size_t)h * D_DIM];
    out[(size_t)row * D_DIM + c] = xs[c] + acc;
  }
}

extern "C" void kernel_launch(void* const* d_in, const int* in_sizes, int n_in,
                              void* d_out, int out_size, void* d_ws, size_t ws_size,
                              hipStream_t stream) {
  const float* x = (const float*)d_in[0];
  const int* eid = (const int*)d_in[1];  // harness materializes ints as int32
  const float* W1 = (const float*)d_in[2];
  const float* b1 = (const float*)d_in[3];
  const float* W2 = (const float*)d_in[4];
  const float* b2 = (const float*)d_in[5];
  float* out = (float*)d_out;

  if (ws_size < (size_t)WS_NEEDED) {
    k_fallback<<<B_ROWS, 256, 0, stream>>>(x, eid, W1, b1, W2, b2, out);
    return;
  }

  char* ws = (char*)d_ws;
  int* counts = (int*)(ws + WS_COUNTS);
  int* base = (int*)(ws + WS_BASE);
  int* cursor = (int*)(ws + WS_CURSOR);
  int* perm = (int*)(ws + WS_PERM);
  short* w1hi = (short*)(ws + WS_W);
  short* w1lo = (short*)(ws + WS_W + WS_WSZ);
  short* w2hi = (short*)(ws + WS_W + 2 * WS_WSZ);
  short* w2lo = (short*)(ws + WS_W + 3 * WS_WSZ);

  k_init<<<(PERM_CAP + 255) / 256, 256, 0, stream>>>(counts, perm);
  k_hist<<<B_ROWS / 256, 256, 0, stream>>>(eid, counts);
  k_scan<<<1, 64, 0, stream>>>(counts, base, cursor);
  k_scatter<<<B_ROWS / 256, 256, 0, stream>>>(eid, cursor, perm);
  k_convert<<<(2 * W_ELEMS + 255) / 256, 256, 0, stream>>>(W1, W2, w1hi, w1lo, w2hi, w2lo);
  k_adapter<<<NBLOCKS_MAIN, 256, 0, stream>>>(x, b1, b2, w1hi, w1lo, w2hi, w2lo,
                                              base, perm, out);
}